// Round 1
// baseline (827.236 us; speedup 1.0000x reference)
//
#include <hip/hip_runtime.h>
#include <hip/hip_fp16.h>
#include <math.h>

// Problem dims (fixed by reference setup_inputs)
#define BB 32
#define TT 2048
#define DD 1024
#define HH 1024
#define MM (BB*TT)

// ============================================================================
// DIAGNOSTIC ROUND (R1): energy_gemm K-loop repeated 4x (REPS=4), epilogue
// scales acc by 1/REPS -> numerically identical output (+~1e-6 rounding).
// Purpose: (a) E = (dur_us - 560)/3 gives the true cost of energy_gemm;
// (b) the ~4E-long dispatch enters rocprof top-5 so we finally see its
// MfmaUtil / VALUBusy / Occupancy / bank-conflict counters.
// Everything else is byte-identical to the 559.7 us baseline.
// ============================================================================
#define DIAG_REPS 4

typedef _Float16 half8 __attribute__((ext_vector_type(8)));
typedef float f32x4 __attribute__((ext_vector_type(4)));

__device__ __forceinline__ float tanh_fast(float x) {
    float cx = fminf(fmaxf(x, -10.0f), 10.0f);
    float e2 = __expf(2.0f * cx);
    return (e2 - 1.0f) / (e2 + 1.0f);
}

// async global->LDS DMA, 16 B per lane. LDS dest = wave-uniform base + lane*16.
__device__ __forceinline__ void load_lds16(const _Float16* g, _Float16* l) {
    __builtin_amdgcn_global_load_lds(
        (const __attribute__((address_space(1))) void*)g,
        (__attribute__((address_space(3))) void*)l, 16, 0, 0);
}

// ---------------------------------------------------------------------------
// compact: per batch, list of unmasked t's (sorted), count, pad to x128.
__global__ void compact_kernel(const int* __restrict__ mask,
                               int* __restrict__ rowlist,
                               int* __restrict__ cnts) {
    const int b = blockIdx.x, tid = threadIdx.x;       // 32 blocks x 256
    const int lane = tid & 63, w = tid >> 6;
    const int* mb = mask + b * TT;
    const int t0 = tid * 8;
    int m[8], c = 0;
#pragma unroll
    for (int j = 0; j < 8; ++j) { m[j] = (mb[t0 + j] != 0); c += m[j]; }
    int pref = c;                                      // wave inclusive scan
#pragma unroll
    for (int off = 1; off < 64; off <<= 1) {
        int nv = __shfl_up(pref, off, 64);
        if (lane >= off) pref += nv;
    }
    __shared__ int wsum[4];
    if (lane == 63) wsum[w] = pref;
    __syncthreads();
    int wbase = 0;
    for (int i = 0; i < w; ++i) wbase += wsum[i];
    int pos = wbase + pref - c;                        // exclusive prefix
#pragma unroll
    for (int j = 0; j < 8; ++j)
        if (m[j]) rowlist[b * TT + pos++] = t0 + j;
    const int total = wsum[0] + wsum[1] + wsum[2] + wsum[3];
    if (tid == 0) cnts[b] = total;
    __syncthreads();                                   // rowlist writes visible
    const int padded = ((total + 127) >> 7) << 7;
    const int lastt = (total > 0) ? rowlist[b * TT + total - 1] : 0;
    for (int ci = total + tid; ci < padded; ci += 256)
        rowlist[b * TT + ci] = lastt;                  // duplicate last row
}

// tile table: global m-tile -> (batch, ci base)
__global__ void tiles_kernel(const int* __restrict__ cnts,
                             int* __restrict__ tile_b,
                             int* __restrict__ tile_ci,
                             int* __restrict__ ntiles) {
    if (threadIdx.x == 0) {
        int tot = 0;
        for (int b = 0; b < BB; ++b) {
            const int nt = (cnts[b] + 127) >> 7;
            for (int i = 0; i < nt; ++i) { tile_b[tot] = b; tile_ci[tot] = i * 128; ++tot; }
        }
        *ntiles = tot;
    }
}

// ---------------------------------------------------------------------------
// cast h fp32->fp16, unmasked rows only (masked never read downstream).
__global__ void cast_h_kernel(const float* __restrict__ h,
                              const int* __restrict__ mask,
                              _Float16* __restrict__ h16) {
    const int row = blockIdx.x * 2 + (threadIdx.x >> 7);   // 2 rows/block
    if (mask[row] == 0) return;                            // wave-uniform
    const int c = (threadIdx.x & 127) * 8;
    const long base = (long)row * DD + c;
    const float4 f0 = *(const float4*)(h + base);
    const float4 f1 = *(const float4*)(h + base + 4);
    half8 o;
    o[0] = (_Float16)f0.x; o[1] = (_Float16)f0.y;
    o[2] = (_Float16)f0.z; o[3] = (_Float16)f0.w;
    o[4] = (_Float16)f1.x; o[5] = (_Float16)f1.y;
    o[6] = (_Float16)f1.z; o[7] = (_Float16)f1.w;
    *(half8*)(h16 + base) = o;
}

// ---------------------------------------------------------------------------
// transpose-cast U (D,H) -> Ut (H,D) fp16
__global__ void prep_ut_kernel(const float* __restrict__ U,
                               _Float16* __restrict__ Ut) {
    __shared__ float tile[32][33];
    const int bx = blockIdx.x, by = blockIdx.y;
    const int tx = threadIdx.x & 31, ty = threadIdx.x >> 5;
#pragma unroll
    for (int j = 0; j < 4; ++j)
        tile[ty + j * 8][tx] = U[(long)(by * 32 + ty + j * 8) * HH + bx * 32 + tx];
    __syncthreads();
#pragma unroll
    for (int j = 0; j < 4; ++j)
        Ut[(long)(bx * 32 + ty + j * 8) * DD + by * 32 + tx] =
            (_Float16)tile[tx][ty + j * 8];
}

// ---------------------------------------------------------------------------
// ps[b][n] = s[b]·W[:,n] ; zero d_out.  grid (32 b, 4 nseg): b-fastest so the
// 32 b-blocks of one nseg share W segments in L2. 8-deep ILP hides latency.
__global__ void prep_ps_kernel(const float* __restrict__ s,
                               const float* __restrict__ W,
                               float* __restrict__ ps,
                               float* __restrict__ out) {
    const int b = blockIdx.x, nseg = blockIdx.y;
    const int n = nseg * 256 + threadIdx.x;
    __shared__ float ss[DD];
#pragma unroll
    for (int j = 0; j < 4; ++j)
        ss[threadIdx.x + j * 256] = s[b * DD + threadIdx.x + j * 256];
    out[b * DD + n] = 0.0f;                    // harness poisons d_out
    __syncthreads();
    float a[8];
#pragma unroll
    for (int j = 0; j < 8; ++j) a[j] = 0.f;
    for (int d = 0; d < DD; d += 8) {
#pragma unroll
        for (int j = 0; j < 8; ++j)
            a[j] += ss[d + j] * W[(long)(d + j) * HH + n];
    }
    ps[b * HH + n] = ((a[0]+a[1])+(a[2]+a[3])) + ((a[4]+a[5])+(a[6]+a[7]));
}

// ---------------------------------------------------------------------------
// energy GEMM on compacted rows, global_load_lds staging (gathered A rows).
#define Bb_K 32

__global__ __launch_bounds__(256)
void energy_gemm_kernel(const _Float16* __restrict__ h16,
                        const _Float16* __restrict__ Ut,
                        const float* __restrict__ ps,
                        const float* __restrict__ v,
                        const int* __restrict__ rowlist,
                        const int* __restrict__ tile_b,
                        const int* __restrict__ tile_ci,
                        const int* __restrict__ ntiles,
                        float* __restrict__ epart) {
    const int mt = blockIdx.y;
    if (mt >= *ntiles) return;                 // uniform, before any barrier
    __shared__ _Float16 As[128][32];           // 8 KB, unpadded (DMA layout)
    __shared__ _Float16 Bs[128][32];           // 8 KB
    __shared__ float ps_s[128];
    __shared__ float v_s[128];
    __shared__ int   rl[128];

    const int nt = blockIdx.x;
    const int b   = tile_b[mt];
    const int ci0 = tile_ci[mt];
    const int n0  = nt * 128;
    const int tid = threadIdx.x;
    const int wave = tid >> 6, lane = tid & 63;
    const int wm = wave >> 1, wn = wave & 1;

    if (tid < 128) {
        ps_s[tid] = ps[b * HH + n0 + tid];
        v_s[tid]  = v[n0 + tid];
        rl[tid]   = rowlist[b * TT + ci0 + tid];
    }
    __syncthreads();

    // staging map: lane i of wave w -> LDS row w*32 + (i>>2), 16B seg (i&3)
    const int srow = wave * 32 + (lane >> 2);
    const int sseg = (lane & 3) * 8;           // halves
    const _Float16* gA0 = h16 + ((long)b * TT + rl[srow])      * DD + sseg;
    const _Float16* gA1 = h16 + ((long)b * TT + rl[srow + 16]) * DD + sseg;
    const _Float16* gB0 = Ut + (long)(n0 + srow) * DD + sseg;
    const _Float16* gB1 = gB0 + 16 * DD;
    _Float16* lA0 = &As[wave * 32][0];
    _Float16* lA1 = &As[wave * 32 + 16][0];
    _Float16* lB0 = &Bs[wave * 32][0];
    _Float16* lB1 = &Bs[wave * 32 + 16][0];

    f32x4 acc[4][4];
#pragma unroll
    for (int i = 0; i < 4; ++i)
#pragma unroll
        for (int j = 0; j < 4; ++j) acc[i][j] = (f32x4)0.0f;

    const int lk = (lane >> 4) * 8;
    const int lr = lane & 15;

    // DIAGNOSTIC: run the K-loop DIAG_REPS times; acc accumulates REPS
    // identical passes; epilogue rescales. Per-iteration structure identical
    // to baseline (barrier / 4x DMA / barrier / ds_read / 16 MFMA).
#pragma unroll 1
    for (int rep = 0; rep < DIAG_REPS; ++rep) {
#pragma unroll 1
        for (int k0 = 0; k0 < DD; k0 += Bb_K) {
            __syncthreads();                       // prev frag reads retired
            load_lds16(gA0 + k0, lA0);
            load_lds16(gA1 + k0, lA1);
            load_lds16(gB0 + k0, lB0);
            load_lds16(gB1 + k0, lB1);
            __syncthreads();                       // vmcnt(0) drain: DMA landed

            half8 af[4], bf[4];
#pragma unroll
            for (int tm = 0; tm < 4; ++tm)
                af[tm] = *(const half8*)&As[wm * 64 + tm * 16 + lr][lk];
#pragma unroll
            for (int tn = 0; tn < 4; ++tn)
                bf[tn] = *(const half8*)&Bs[wn * 64 + tn * 16 + lr][lk];
#pragma unroll
            for (int tm = 0; tm < 4; ++tm)
#pragma unroll
                for (int tn = 0; tn < 4; ++tn)
                    acc[tm][tn] = __builtin_amdgcn_mfma_f32_16x16x32_f16(
                        af[tm], bf[tn], acc[tm][tn], 0, 0, 0);
        }
    }

    const float rscale = 1.0f / (float)DIAG_REPS;

    // epilogue: partial energy per row over this wave's 64 cols
    float part[4][4];
#pragma unroll
    for (int tm = 0; tm < 4; ++tm) {
#pragma unroll
        for (int r = 0; r < 4; ++r) {
            float p = 0.f;
#pragma unroll
            for (int tn = 0; tn < 4; ++tn) {
                const int cl = wn * 64 + tn * 16 + lr;
                p += v_s[cl] * tanh_fast(rscale * acc[tm][tn][r] + ps_s[cl]);
            }
            part[tm][r] = p;
        }
    }
#pragma unroll
    for (int off = 1; off < 16; off <<= 1)
#pragma unroll
        for (int tm = 0; tm < 4; ++tm)
#pragma unroll
            for (int r = 0; r < 4; ++r)
                part[tm][r] += __shfl_xor(part[tm][r], off, 64);

    if ((lane & 15) == 0) {
        const int slot = nt * 2 + wn;          // 16 deterministic slots
#pragma unroll
        for (int tm = 0; tm < 4; ++tm)
#pragma unroll
            for (int r = 0; r < 4; ++r) {
                const int ci = ci0 + wm * 64 + tm * 16 + (lane >> 4) * 4 + r;
                epart[(long)slot * MM + b * TT + ci] = part[tm][r];
            }
    }
}

// ---------------------------------------------------------------------------
// softmax over the compacted (unmasked) set; masked t's get score 0.
__global__ void softmax_kernel(const float* __restrict__ epart,
                               const int* __restrict__ rowlist,
                               const int* __restrict__ cnts,
                               float* __restrict__ score) {
    const int b = blockIdx.x, tid = threadIdx.x;   // 32 x 256
    const int cnt = cnts[b];
    for (int t = tid; t < TT; t += 256) score[b * TT + t] = 0.0f;

    float e[8], mx = -1e30f;
#pragma unroll
    for (int i = 0; i < 8; ++i) {
        const int ci = i * 256 + tid;
        float sum = -1e30f;
        if (ci < cnt) {
            sum = 0.f;
#pragma unroll
            for (int p = 0; p < 16; ++p)
                sum += epart[(long)p * MM + b * TT + ci];
        }
        e[i] = sum;
        mx = fmaxf(mx, sum);
    }
#pragma unroll
    for (int off = 32; off > 0; off >>= 1) mx = fmaxf(mx, __shfl_xor(mx, off, 64));
    __shared__ float r4[4];
    if ((tid & 63) == 0) r4[tid >> 6] = mx;
    __syncthreads();
    mx = fmaxf(fmaxf(r4[0], r4[1]), fmaxf(r4[2], r4[3]));

    float tot = 0.f;
#pragma unroll
    for (int i = 0; i < 8; ++i) {
        const int ci = i * 256 + tid;
        e[i] = (ci < cnt) ? __expf(e[i] - mx) : 0.0f;
        tot += e[i];
    }
#pragma unroll
    for (int off = 32; off > 0; off >>= 1) tot += __shfl_xor(tot, off, 64);
    __shared__ float s4[4];
    if ((tid & 63) == 0) s4[tid >> 6] = tot;
    __syncthreads();                                // also orders the zero-fill
    tot = s4[0] + s4[1] + s4[2] + s4[3];
    const float inv = 1.0f / tot;
#pragma unroll
    for (int i = 0; i < 8; ++i) {
        const int ci = i * 256 + tid;
        if (ci < cnt)
            score[b * TT + rowlist[b * TT + ci]] = e[i] * inv;
    }
}

// ---------------------------------------------------------------------------
// context[b][d] = sum_t score·h16 ; score==0 (masked) rows skipped
__global__ void context_kernel(const _Float16* __restrict__ h16,
                               const float* __restrict__ score,
                               float* __restrict__ out) {
    const int tc = blockIdx.x;                 // 16 chunks x 128 t
    const int b  = blockIdx.y;
    const int d0 = threadIdx.x * 8;            // 128 thr x 8
    float a[8];
#pragma unroll
    for (int j = 0; j < 8; ++j) a[j] = 0.f;
    for (int i = 0; i < 128; ++i) {
        const int t = tc * 128 + i;
        const float sc = score[(long)b * TT + t];
        if (sc != 0.0f) {
            const half8 hv = *(const half8*)(h16 + ((long)(b * TT + t)) * DD + d0);
#pragma unroll
            for (int j = 0; j < 8; ++j) a[j] += sc * (float)hv[j];
        }
    }
#pragma unroll
    for (int j = 0; j < 8; ++j) atomicAdd(&out[b * DD + d0 + j], a[j]);
}

// ---------------------------------------------------------------------------
extern "C" void kernel_launch(void* const* d_in, const int* in_sizes, int n_in,
                              void* d_out, int out_size, void* d_ws, size_t ws_size,
                              hipStream_t stream) {
    const float* s    = (const float*)d_in[0];
    const float* h    = (const float*)d_in[1];
    const int*   mask = (const int*)  d_in[2];
    const float* W    = (const float*)d_in[3];
    const float* U    = (const float*)d_in[4];
    const float* v    = (const float*)d_in[5];
    float* out = (float*)d_out;

    // workspace layout (~135 MB; round-2 confirmed ws >= 140 MB)
    char* ws = (char*)d_ws;
    size_t off = 0;
    _Float16* h16 = (_Float16*)(ws + off); off += (size_t)MM * DD * 2;   // 128 MB
    _Float16* Ut  = (_Float16*)(ws + off); off += (size_t)HH * DD * 2;   // 2 MB
    float*    ps  = (float*)(ws + off);    off += (size_t)BB * HH * 4;   // 128 KB
    float*    ep  = (float*)(ws + off);    off += (size_t)16 * MM * 4;   // 4 MB
    float*    scr = (float*)(ws + off);    off += (size_t)MM * 4;        // 256 KB
    int*      rlist = (int*)(ws + off);    off += (size_t)MM * 4;        // 256 KB
    int*      cnts  = (int*)(ws + off);    off += 64 * 4;
    int*      tb    = (int*)(ws + off);    off += 512 * 4;
    int*      tci   = (int*)(ws + off);    off += 512 * 4;
    int*      ntl   = (int*)(ws + off);

    compact_kernel<<<BB, 256, 0, stream>>>(mask, rlist, cnts);
    tiles_kernel  <<<1, 64, 0, stream>>>(cnts, tb, tci, ntl);
    cast_h_kernel <<<MM / 2, 256, 0, stream>>>(h, mask, h16);
    prep_ut_kernel<<<dim3(32, 32), 256, 0, stream>>>(U, Ut);
    prep_ps_kernel<<<dim3(32, 4), 256, 0, stream>>>(s, W, ps, out);
    energy_gemm_kernel<<<dim3(8, 512), 256, 0, stream>>>(h16, Ut, ps, v,
                                                         rlist, tb, tci, ntl, ep);
    softmax_kernel<<<BB, 256, 0, stream>>>(ep, rlist, cnts, scr);
    context_kernel<<<dim3(16, 32), 128, 0, stream>>>(h16, scr, out);
}

// Round 2
// 616.830 us; speedup vs baseline: 1.3411x; 1.3411x over previous
//
#include <hip/hip_runtime.h>
#include <hip/hip_fp16.h>
#include <math.h>

// Problem dims (fixed by reference setup_inputs)
#define BB 32
#define TT 2048
#define DD 1024
#define HH 1024
#define MM (BB*TT)

typedef _Float16 half8 __attribute__((ext_vector_type(8)));
typedef float f32x4 __attribute__((ext_vector_type(4)));

__device__ __forceinline__ float tanh_fast(float x) {
    float cx = fminf(fmaxf(x, -10.0f), 10.0f);
    float e2 = __expf(2.0f * cx);
    return (e2 - 1.0f) / (e2 + 1.0f);
}

// async global->LDS DMA, 16 B per lane. LDS dest = wave-uniform base + lane*16.
__device__ __forceinline__ void load_lds16(const _Float16* g, _Float16* l) {
    __builtin_amdgcn_global_load_lds(
        (const __attribute__((address_space(1))) void*)g,
        (__attribute__((address_space(3))) void*)l, 16, 0, 0);
}

// ---------------------------------------------------------------------------
// mega_setup: one launch for the four independent prep kernels.
//   [0, 32768)          cast_h  (2 rows/block)
//   [32768, 33792)      prep_ut (32x32 tiles)
//   [33792, 33920)      prep_ps (32 b x 4 nseg)
//   [33920, 33952)      compact (32 batches)
#define CAST_BLOCKS (MM/2)
#define UT_BLOCKS   1024
#define PS_BLOCKS   128
#define CPT_BLOCKS  32
#define TOTAL_SETUP (CAST_BLOCKS + UT_BLOCKS + PS_BLOCKS + CPT_BLOCKS)

__global__ __launch_bounds__(256)
void mega_setup_kernel(const float* __restrict__ h,
                       const int* __restrict__ mask,
                       _Float16* __restrict__ h16,
                       const float* __restrict__ U,
                       _Float16* __restrict__ Ut,
                       const float* __restrict__ s,
                       const float* __restrict__ W,
                       float* __restrict__ ps,
                       float* __restrict__ out,
                       int* __restrict__ rowlist,
                       int* __restrict__ cnts) {
    __shared__ float smem[1056];           // prep_ut 32x33 tile / prep_ps ss[1024]
    __shared__ int wsum[4];
    const int bid = blockIdx.x;
    const int tid = threadIdx.x;

    if (bid < CAST_BLOCKS) {
        // ---- cast h fp32->fp16, unmasked rows only ----
        const int row = bid * 2 + (tid >> 7);
        if (mask[row] == 0) return;                        // wave-uniform
        const int c = (tid & 127) * 8;
        const long base = (long)row * DD + c;
        const float4 f0 = *(const float4*)(h + base);
        const float4 f1 = *(const float4*)(h + base + 4);
        half8 o;
        o[0] = (_Float16)f0.x; o[1] = (_Float16)f0.y;
        o[2] = (_Float16)f0.z; o[3] = (_Float16)f0.w;
        o[4] = (_Float16)f1.x; o[5] = (_Float16)f1.y;
        o[6] = (_Float16)f1.z; o[7] = (_Float16)f1.w;
        *(half8*)(h16 + base) = o;
        return;
    }

    if (bid < CAST_BLOCKS + UT_BLOCKS) {
        // ---- transpose-cast U (D,H) -> Ut (H,D) fp16 ----
        const int id = bid - CAST_BLOCKS;
        const int bx = id & 31, by = id >> 5;
        float (*tile)[33] = (float(*)[33])smem;
        const int tx = tid & 31, ty = tid >> 5;
#pragma unroll
        for (int j = 0; j < 4; ++j)
            tile[ty + j * 8][tx] = U[(long)(by * 32 + ty + j * 8) * HH + bx * 32 + tx];
        __syncthreads();
#pragma unroll
        for (int j = 0; j < 4; ++j)
            Ut[(long)(bx * 32 + ty + j * 8) * DD + by * 32 + tx] =
                (_Float16)tile[tx][ty + j * 8];
        return;
    }

    if (bid < CAST_BLOCKS + UT_BLOCKS + PS_BLOCKS) {
        // ---- ps[b][n] = s[b]·W[:,n] ; zero d_out ----
        const int id = bid - (CAST_BLOCKS + UT_BLOCKS);
        const int b = id & 31, nseg = id >> 5;
        const int n = nseg * 256 + tid;
        float* ss = smem;
#pragma unroll
        for (int j = 0; j < 4; ++j)
            ss[tid + j * 256] = s[b * DD + tid + j * 256];
        out[b * DD + n] = 0.0f;                    // harness poisons d_out
        __syncthreads();
        float a[8];
#pragma unroll
        for (int j = 0; j < 8; ++j) a[j] = 0.f;
        for (int d = 0; d < DD; d += 8) {
#pragma unroll
            for (int j = 0; j < 8; ++j)
                a[j] += ss[d + j] * W[(long)(d + j) * HH + n];
        }
        ps[b * HH + n] = ((a[0]+a[1])+(a[2]+a[3])) + ((a[4]+a[5])+(a[6]+a[7]));
        return;
    }

    // ---- compact: per batch, sorted list of unmasked t's, count, pad x128 ----
    {
        const int b = bid - (CAST_BLOCKS + UT_BLOCKS + PS_BLOCKS);
        const int lane = tid & 63, w = tid >> 6;
        const int* mb = mask + b * TT;
        const int t0 = tid * 8;
        int m[8], c = 0;
#pragma unroll
        for (int j = 0; j < 8; ++j) { m[j] = (mb[t0 + j] != 0); c += m[j]; }
        int pref = c;                                      // wave inclusive scan
#pragma unroll
        for (int off = 1; off < 64; off <<= 1) {
            int nv = __shfl_up(pref, off, 64);
            if (lane >= off) pref += nv;
        }
        if (lane == 63) wsum[w] = pref;
        __syncthreads();
        int wbase = 0;
        for (int i = 0; i < w; ++i) wbase += wsum[i];
        int pos = wbase + pref - c;                        // exclusive prefix
#pragma unroll
        for (int j = 0; j < 8; ++j)
            if (m[j]) rowlist[b * TT + pos++] = t0 + j;
        const int total = wsum[0] + wsum[1] + wsum[2] + wsum[3];
        if (tid == 0) cnts[b] = total;
        __syncthreads();                                   // rowlist writes visible
        const int padded = ((total + 127) >> 7) << 7;
        const int lastt = (total > 0) ? rowlist[b * TT + total - 1] : 0;
        for (int ci = total + tid; ci < padded; ci += 256)
            rowlist[b * TT + ci] = lastt;                  // duplicate last row
    }
}

// ---------------------------------------------------------------------------
// energy GEMM on compacted rows, global_load_lds staging (gathered A rows).
// Grid (512 mt, 8 nt): mt-fastest so consecutive blocks stream DISTINCT
// A-tiles (one nt-pass at a time) -> A re-reads across nt hit L3 instead of
// 8 parallel XCD-L2 fills. Static tile map: mt -> (b = mt>>4, ci0 = (mt&15)*128),
// invalid tiles early-return on cnts[b] (tile order is irrelevant).
// T2 swizzle (both-sides, rule #21): stage SOURCE seg ^= (row&3), ds_read seg
// ^= (row&3). Involution; removes the 2x bank-conflict on the b128 frag reads.
#define Bb_K 32

__global__ __launch_bounds__(256)
void energy_gemm_kernel(const _Float16* __restrict__ h16,
                        const _Float16* __restrict__ Ut,
                        const float* __restrict__ ps,
                        const float* __restrict__ v,
                        const int* __restrict__ rowlist,
                        const int* __restrict__ cnts,
                        float* __restrict__ epart) {
    const int mt = blockIdx.x;
    const int nt = blockIdx.y;
    const int b   = mt >> 4;
    const int ci0 = (mt & 15) << 7;
    if (ci0 >= cnts[b]) return;                // uniform, before any barrier

    __shared__ _Float16 As[128][32];           // 8 KB, unpadded (DMA layout)
    __shared__ _Float16 Bs[128][32];           // 8 KB
    __shared__ float ps_s[128];
    __shared__ float v_s[128];
    __shared__ int   rl[128];

    const int n0  = nt * 128;
    const int tid = threadIdx.x;
    const int wave = tid >> 6, lane = tid & 63;
    const int wm = wave >> 1, wn = wave & 1;

    if (tid < 128) {
        ps_s[tid] = ps[b * HH + n0 + tid];
        v_s[tid]  = v[n0 + tid];
        rl[tid]   = rowlist[b * TT + ci0 + tid];
    }
    __syncthreads();

    // staging map: lane i of wave w -> LDS row w*32 + (i>>2), 16B seg (i&3).
    // T2: the 16B seg each lane FETCHES is XOR'd by (row&3) so that LDS seg
    // position p of row r holds global seg p^(r&3).
    const int srow = wave * 32 + (lane >> 2);
    const int sseg = ((lane & 3) ^ ((lane >> 2) & 3)) * 8;   // halves
    const _Float16* gA0 = h16 + ((long)b * TT + rl[srow])      * DD + sseg;
    const _Float16* gA1 = h16 + ((long)b * TT + rl[srow + 16]) * DD + sseg;
    const _Float16* gB0 = Ut + (long)(n0 + srow) * DD + sseg;
    const _Float16* gB1 = gB0 + 16 * DD;
    _Float16* lA0 = &As[wave * 32][0];
    _Float16* lA1 = &As[wave * 32 + 16][0];
    _Float16* lB0 = &Bs[wave * 32][0];
    _Float16* lB1 = &Bs[wave * 32 + 16][0];

    f32x4 acc[4][4];
#pragma unroll
    for (int i = 0; i < 4; ++i)
#pragma unroll
        for (int j = 0; j < 4; ++j) acc[i][j] = (f32x4)0.0f;

    const int lr = lane & 15;
    // T2 read side: frag rows are wm*64+tm*16+lr (= lr mod 4) -> same XOR for
    // all tm/tn. Position read = (lane>>4) ^ (lr&3); content = seg lane>>4.
    const int lk = (((lane >> 4) ^ (lr & 3))) * 8;

#pragma unroll 1
    for (int k0 = 0; k0 < DD; k0 += Bb_K) {
        __syncthreads();                       // prev frag reads retired
        load_lds16(gA0 + k0, lA0);
        load_lds16(gA1 + k0, lA1);
        load_lds16(gB0 + k0, lB0);
        load_lds16(gB1 + k0, lB1);
        __syncthreads();                       // vmcnt(0) drain: DMA landed

        half8 af[4], bf[4];
#pragma unroll
        for (int tm = 0; tm < 4; ++tm)
            af[tm] = *(const half8*)&As[wm * 64 + tm * 16 + lr][lk];
#pragma unroll
        for (int tn = 0; tn < 4; ++tn)
            bf[tn] = *(const half8*)&Bs[wn * 64 + tn * 16 + lr][lk];
        __builtin_amdgcn_s_setprio(1);
#pragma unroll
        for (int tm = 0; tm < 4; ++tm)
#pragma unroll
            for (int tn = 0; tn < 4; ++tn)
                acc[tm][tn] = __builtin_amdgcn_mfma_f32_16x16x32_f16(
                    af[tm], bf[tn], acc[tm][tn], 0, 0, 0);
        __builtin_amdgcn_s_setprio(0);
    }

    // epilogue: partial energy per row over this wave's 64 cols
    float part[4][4];
#pragma unroll
    for (int tm = 0; tm < 4; ++tm) {
#pragma unroll
        for (int r = 0; r < 4; ++r) {
            float p = 0.f;
#pragma unroll
            for (int tn = 0; tn < 4; ++tn) {
                const int cl = wn * 64 + tn * 16 + lr;
                p += v_s[cl] * tanh_fast(acc[tm][tn][r] + ps_s[cl]);
            }
            part[tm][r] = p;
        }
    }
#pragma unroll
    for (int off = 1; off < 16; off <<= 1)
#pragma unroll
        for (int tm = 0; tm < 4; ++tm)
#pragma unroll
            for (int r = 0; r < 4; ++r)
                part[tm][r] += __shfl_xor(part[tm][r], off, 64);

    if ((lane & 15) == 0) {
        const int slot = nt * 2 + wn;          // 16 deterministic slots
#pragma unroll
        for (int tm = 0; tm < 4; ++tm)
#pragma unroll
            for (int r = 0; r < 4; ++r) {
                const int ci = ci0 + wm * 64 + tm * 16 + (lane >> 4) * 4 + r;
                epart[(long)slot * MM + b * TT + ci] = part[tm][r];
            }
    }
}

// ---------------------------------------------------------------------------
// softmax over the compacted (unmasked) set; masked t's get score 0.
__global__ void softmax_kernel(const float* __restrict__ epart,
                               const int* __restrict__ rowlist,
                               const int* __restrict__ cnts,
                               float* __restrict__ score) {
    const int b = blockIdx.x, tid = threadIdx.x;   // 32 x 256
    const int cnt = cnts[b];
    for (int t = tid; t < TT; t += 256) score[b * TT + t] = 0.0f;

    float e[8], mx = -1e30f;
#pragma unroll
    for (int i = 0; i < 8; ++i) {
        const int ci = i * 256 + tid;
        float sum = -1e30f;
        if (ci < cnt) {
            sum = 0.f;
#pragma unroll
            for (int p = 0; p < 16; ++p)
                sum += epart[(long)p * MM + b * TT + ci];
        }
        e[i] = sum;
        mx = fmaxf(mx, sum);
    }
#pragma unroll
    for (int off = 32; off > 0; off >>= 1) mx = fmaxf(mx, __shfl_xor(mx, off, 64));
    __shared__ float r4[4];
    if ((tid & 63) == 0) r4[tid >> 6] = mx;
    __syncthreads();
    mx = fmaxf(fmaxf(r4[0], r4[1]), fmaxf(r4[2], r4[3]));

    float tot = 0.f;
#pragma unroll
    for (int i = 0; i < 8; ++i) {
        const int ci = i * 256 + tid;
        e[i] = (ci < cnt) ? __expf(e[i] - mx) : 0.0f;
        tot += e[i];
    }
#pragma unroll
    for (int off = 32; off > 0; off >>= 1) tot += __shfl_xor(tot, off, 64);
    __shared__ float s4[4];
    if ((tid & 63) == 0) s4[tid >> 6] = tot;
    __syncthreads();                                // also orders the zero-fill
    tot = s4[0] + s4[1] + s4[2] + s4[3];
    const float inv = 1.0f / tot;
#pragma unroll
    for (int i = 0; i < 8; ++i) {
        const int ci = i * 256 + tid;
        if (ci < cnt)
            score[b * TT + rowlist[b * TT + ci]] = e[i] * inv;
    }
}

// ---------------------------------------------------------------------------
// context[b][d] = sum_t score·h16 ; score==0 (masked) rows skipped
__global__ void context_kernel(const _Float16* __restrict__ h16,
                               const float* __restrict__ score,
                               float* __restrict__ out) {
    const int tc = blockIdx.x;                 // 16 chunks x 128 t
    const int b  = blockIdx.y;
    const int d0 = threadIdx.x * 8;            // 128 thr x 8
    float a[8];
#pragma unroll
    for (int j = 0; j < 8; ++j) a[j] = 0.f;
    for (int i = 0; i < 128; ++i) {
        const int t = tc * 128 + i;
        const float sc = score[(long)b * TT + t];
        if (sc != 0.0f) {
            const half8 hv = *(const half8*)(h16 + ((long)(b * TT + t)) * DD + d0);
#pragma unroll
            for (int j = 0; j < 8; ++j) a[j] += sc * (float)hv[j];
        }
    }
#pragma unroll
    for (int j = 0; j < 8; ++j) atomicAdd(&out[b * DD + d0 + j], a[j]);
}

// ---------------------------------------------------------------------------
extern "C" void kernel_launch(void* const* d_in, const int* in_sizes, int n_in,
                              void* d_out, int out_size, void* d_ws, size_t ws_size,
                              hipStream_t stream) {
    const float* s    = (const float*)d_in[0];
    const float* h    = (const float*)d_in[1];
    const int*   mask = (const int*)  d_in[2];
    const float* W    = (const float*)d_in[3];
    const float* U    = (const float*)d_in[4];
    const float* v    = (const float*)d_in[5];
    float* out = (float*)d_out;

    // workspace layout (~135 MB)
    char* ws = (char*)d_ws;
    size_t off = 0;
    _Float16* h16 = (_Float16*)(ws + off); off += (size_t)MM * DD * 2;   // 128 MB
    _Float16* Ut  = (_Float16*)(ws + off); off += (size_t)HH * DD * 2;   // 2 MB
    float*    ps  = (float*)(ws + off);    off += (size_t)BB * HH * 4;   // 128 KB
    float*    ep  = (float*)(ws + off);    off += (size_t)16 * MM * 4;   // 4 MB
    float*    scr = (float*)(ws + off);    off += (size_t)MM * 4;        // 256 KB
    int*      rlist = (int*)(ws + off);    off += (size_t)MM * 4;        // 256 KB
    int*      cnts  = (int*)(ws + off);    off += 64 * 4;

    mega_setup_kernel<<<TOTAL_SETUP, 256, 0, stream>>>(h, mask, h16, U, Ut,
                                                       s, W, ps, out, rlist, cnts);
    energy_gemm_kernel<<<dim3(512, 8), 256, 0, stream>>>(h16, Ut, ps, v,
                                                         rlist, cnts, ep);
    softmax_kernel<<<BB, 256, 0, stream>>>(ep, rlist, cnts, scr);
    context_kernel<<<dim3(16, 32), 128, 0, stream>>>(h16, scr, out);
}

// Round 3
// 562.102 us; speedup vs baseline: 1.4717x; 1.0974x over previous
//
#include <hip/hip_runtime.h>
#include <hip/hip_fp16.h>
#include <math.h>

// Problem dims (fixed by reference setup_inputs)
#define BB 32
#define TT 2048
#define DD 1024
#define HH 1024
#define MM (BB*TT)

typedef _Float16 half8 __attribute__((ext_vector_type(8)));
typedef float f32x4 __attribute__((ext_vector_type(4)));

__device__ __forceinline__ float tanh_fast(float x) {
    float cx = fminf(fmaxf(x, -10.0f), 10.0f);
    float e2 = __expf(2.0f * cx);
    return (e2 - 1.0f) / (e2 + 1.0f);
}

// async global->LDS DMA, 16 B per lane. LDS dest = wave-uniform base + lane*16.
__device__ __forceinline__ void load_lds16(const _Float16* g, _Float16* l) {
    __builtin_amdgcn_global_load_lds(
        (const __attribute__((address_space(1))) void*)g,
        (__attribute__((address_space(3))) void*)l, 16, 0, 0);
}

// ---------------------------------------------------------------------------
// mega_setup: one launch for the four independent prep kernels.
#define CAST_BLOCKS (MM/2)
#define UT_BLOCKS   1024
#define PS_BLOCKS   128
#define CPT_BLOCKS  32
#define TOTAL_SETUP (CAST_BLOCKS + UT_BLOCKS + PS_BLOCKS + CPT_BLOCKS)

__global__ __launch_bounds__(256)
void mega_setup_kernel(const float* __restrict__ h,
                       const int* __restrict__ mask,
                       _Float16* __restrict__ h16,
                       const float* __restrict__ U,
                       _Float16* __restrict__ Ut,
                       const float* __restrict__ s,
                       const float* __restrict__ W,
                       float* __restrict__ ps,
                       float* __restrict__ out,
                       int* __restrict__ rowlist,
                       int* __restrict__ cnts) {
    __shared__ float smem[1056];           // prep_ut 32x33 tile / prep_ps ss[1024]
    __shared__ int wsum[4];
    const int bid = blockIdx.x;
    const int tid = threadIdx.x;

    if (bid < CAST_BLOCKS) {
        // ---- cast h fp32->fp16, unmasked rows only ----
        const int row = bid * 2 + (tid >> 7);
        if (mask[row] == 0) return;                        // wave-uniform
        const int c = (tid & 127) * 8;
        const long base = (long)row * DD + c;
        const float4 f0 = *(const float4*)(h + base);
        const float4 f1 = *(const float4*)(h + base + 4);
        half8 o;
        o[0] = (_Float16)f0.x; o[1] = (_Float16)f0.y;
        o[2] = (_Float16)f0.z; o[3] = (_Float16)f0.w;
        o[4] = (_Float16)f1.x; o[5] = (_Float16)f1.y;
        o[6] = (_Float16)f1.z; o[7] = (_Float16)f1.w;
        *(half8*)(h16 + base) = o;
        return;
    }

    if (bid < CAST_BLOCKS + UT_BLOCKS) {
        // ---- transpose-cast U (D,H) -> Ut (H,D) fp16 ----
        const int id = bid - CAST_BLOCKS;
        const int bx = id & 31, by = id >> 5;
        float (*tile)[33] = (float(*)[33])smem;
        const int tx = tid & 31, ty = tid >> 5;
#pragma unroll
        for (int j = 0; j < 4; ++j)
            tile[ty + j * 8][tx] = U[(long)(by * 32 + ty + j * 8) * HH + bx * 32 + tx];
        __syncthreads();
#pragma unroll
        for (int j = 0; j < 4; ++j)
            Ut[(long)(bx * 32 + ty + j * 8) * DD + by * 32 + tx] =
                (_Float16)tile[tx][ty + j * 8];
        return;
    }

    if (bid < CAST_BLOCKS + UT_BLOCKS + PS_BLOCKS) {
        // ---- ps[b][n] = s[b]·W[:,n] ; zero d_out ----
        const int id = bid - (CAST_BLOCKS + UT_BLOCKS);
        const int b = id & 31, nseg = id >> 5;
        const int n = nseg * 256 + tid;
        float* ss = smem;
#pragma unroll
        for (int j = 0; j < 4; ++j)
            ss[tid + j * 256] = s[b * DD + tid + j * 256];
        out[b * DD + n] = 0.0f;                    // harness poisons d_out
        __syncthreads();
        float a[8];
#pragma unroll
        for (int j = 0; j < 8; ++j) a[j] = 0.f;
        for (int d = 0; d < DD; d += 8) {
#pragma unroll
            for (int j = 0; j < 8; ++j)
                a[j] += ss[d + j] * W[(long)(d + j) * HH + n];
        }
        ps[b * HH + n] = ((a[0]+a[1])+(a[2]+a[3])) + ((a[4]+a[5])+(a[6]+a[7]));
        return;
    }

    // ---- compact: per batch, sorted list of unmasked t's, count, pad x128 ----
    {
        const int b = bid - (CAST_BLOCKS + UT_BLOCKS + PS_BLOCKS);
        const int lane = tid & 63, w = tid >> 6;
        const int* mb = mask + b * TT;
        const int t0 = tid * 8;
        int m[8], c = 0;
#pragma unroll
        for (int j = 0; j < 8; ++j) { m[j] = (mb[t0 + j] != 0); c += m[j]; }
        int pref = c;                                      // wave inclusive scan
#pragma unroll
        for (int off = 1; off < 64; off <<= 1) {
            int nv = __shfl_up(pref, off, 64);
            if (lane >= off) pref += nv;
        }
        if (lane == 63) wsum[w] = pref;
        __syncthreads();
        int wbase = 0;
        for (int i = 0; i < w; ++i) wbase += wsum[i];
        int pos = wbase + pref - c;                        // exclusive prefix
#pragma unroll
        for (int j = 0; j < 8; ++j)
            if (m[j]) rowlist[b * TT + pos++] = t0 + j;
        const int total = wsum[0] + wsum[1] + wsum[2] + wsum[3];
        if (tid == 0) cnts[b] = total;
        __syncthreads();                                   // rowlist writes visible
        const int padded = ((total + 127) >> 7) << 7;
        const int lastt = (total > 0) ? rowlist[b * TT + total - 1] : 0;
        for (int ci = total + tid; ci < padded; ci += 256)
            rowlist[b * TT + ci] = lastt;                  // duplicate last row
    }
}

// ---------------------------------------------------------------------------
// energy GEMM on compacted rows, global_load_lds staging (gathered A rows).
// Grid (8 nt, 512 mt): nt-fastest (round-0/1 order, empirically best) -- the
// 8 nt-siblings of one A-tile are dispatch-adjacent, fetch the tile co-timed.
// T3-minimum 2-phase pipeline: double-buffered As/Bs; next K-tile's
// global_load_lds issued BEFORE current tile's ds_read+MFMA; single raw
// s_barrier + manual vmcnt(0) per K-step placed AFTER the MFMAs, so load
// latency hides under compute (baseline exposed it fully every K-step).
// Buffer index is compile-time (2-step unroll, rule #20).
#define Bb_K 32

__global__ __launch_bounds__(256)
void energy_gemm_kernel(const _Float16* __restrict__ h16,
                        const _Float16* __restrict__ Ut,
                        const float* __restrict__ ps,
                        const float* __restrict__ v,
                        const int* __restrict__ rowlist,
                        const int* __restrict__ cnts,
                        float* __restrict__ epart) {
    const int nt = blockIdx.x;
    const int mt = blockIdx.y;
    const int b   = mt >> 4;
    const int ci0 = (mt & 15) << 7;
    if (ci0 >= cnts[b]) return;                // uniform, before any barrier

    __shared__ _Float16 As[2][128][32];        // 2 x 8 KB, unpadded (DMA layout)
    __shared__ _Float16 Bs[2][128][32];        // 2 x 8 KB
    __shared__ float ps_s[128];
    __shared__ float v_s[128];
    __shared__ int   rl[128];

    const int n0  = nt * 128;
    const int tid = threadIdx.x;
    const int wave = tid >> 6, lane = tid & 63;
    const int wm = wave >> 1, wn = wave & 1;

    if (tid < 128) {
        ps_s[tid] = ps[b * HH + n0 + tid];
        v_s[tid]  = v[n0 + tid];
        rl[tid]   = rowlist[b * TT + ci0 + tid];
    }
    __syncthreads();

    // staging map: lane i of wave w -> LDS row w*32 + (i>>2), 16B seg (i&3)
    const int srow = wave * 32 + (lane >> 2);
    const int sseg = (lane & 3) * 8;           // halves
    const _Float16* gA0 = h16 + ((long)b * TT + rl[srow])      * DD + sseg;
    const _Float16* gA1 = h16 + ((long)b * TT + rl[srow + 16]) * DD + sseg;
    const _Float16* gB0 = Ut + (long)(n0 + srow) * DD + sseg;
    const _Float16* gB1 = gB0 + 16 * DD;

    f32x4 acc[4][4];
#pragma unroll
    for (int i = 0; i < 4; ++i)
#pragma unroll
        for (int j = 0; j < 4; ++j) acc[i][j] = (f32x4)0.0f;

    const int lk = (lane >> 4) * 8;
    const int lr = lane & 15;

    // prologue: stage K-tile 0 into buf0, drain, barrier
    load_lds16(gA0, &As[0][wave * 32][0]);
    load_lds16(gA1, &As[0][wave * 32 + 16][0]);
    load_lds16(gB0, &Bs[0][wave * 32][0]);
    load_lds16(gB1, &Bs[0][wave * 32 + 16][0]);
    asm volatile("s_waitcnt vmcnt(0)" ::: "memory");
    __builtin_amdgcn_s_barrier();

    // One K-step: stage tile KS+1 into buf NXT, compute tile KS from buf CUR,
    // then vmcnt(0)+barrier (loads for NXT landed; all reads of CUR retired
    // in-registers via the compiler's lgkmcnt before the MFMAs).
#define KSTEP(CUR, NXT, KS)                                                   \
    {                                                                         \
        const int k1 = ((KS) + 1) * Bb_K;                                     \
        if (k1 < DD) {                                                        \
            load_lds16(gA0 + k1, &As[NXT][wave * 32][0]);                     \
            load_lds16(gA1 + k1, &As[NXT][wave * 32 + 16][0]);                \
            load_lds16(gB0 + k1, &Bs[NXT][wave * 32][0]);                     \
            load_lds16(gB1 + k1, &Bs[NXT][wave * 32 + 16][0]);                \
        }                                                                     \
        half8 af[4], bf[4];                                                   \
        _Pragma("unroll")                                                     \
        for (int tm = 0; tm < 4; ++tm)                                        \
            af[tm] = *(const half8*)&As[CUR][wm * 64 + tm * 16 + lr][lk];     \
        _Pragma("unroll")                                                     \
        for (int tn = 0; tn < 4; ++tn)                                        \
            bf[tn] = *(const half8*)&Bs[CUR][wn * 64 + tn * 16 + lr][lk];     \
        _Pragma("unroll")                                                     \
        for (int tm = 0; tm < 4; ++tm)                                        \
            _Pragma("unroll")                                                 \
            for (int tn = 0; tn < 4; ++tn)                                    \
                acc[tm][tn] = __builtin_amdgcn_mfma_f32_16x16x32_f16(         \
                    af[tm], bf[tn], acc[tm][tn], 0, 0, 0);                    \
        asm volatile("s_waitcnt vmcnt(0)" ::: "memory");                      \
        __builtin_amdgcn_s_barrier();                                         \
    }

#pragma unroll 1
    for (int ks = 0; ks < 32; ks += 2) {
        KSTEP(0, 1, ks);
        KSTEP(1, 0, ks + 1);
    }
#undef KSTEP

    // epilogue: partial energy per row over this wave's 64 cols
    float part[4][4];
#pragma unroll
    for (int tm = 0; tm < 4; ++tm) {
#pragma unroll
        for (int r = 0; r < 4; ++r) {
            float p = 0.f;
#pragma unroll
            for (int tn = 0; tn < 4; ++tn) {
                const int cl = wn * 64 + tn * 16 + lr;
                p += v_s[cl] * tanh_fast(acc[tm][tn][r] + ps_s[cl]);
            }
            part[tm][r] = p;
        }
    }
#pragma unroll
    for (int off = 1; off < 16; off <<= 1)
#pragma unroll
        for (int tm = 0; tm < 4; ++tm)
#pragma unroll
            for (int r = 0; r < 4; ++r)
                part[tm][r] += __shfl_xor(part[tm][r], off, 64);

    if ((lane & 15) == 0) {
        const int slot = nt * 2 + wn;          // 16 deterministic slots
#pragma unroll
        for (int tm = 0; tm < 4; ++tm)
#pragma unroll
            for (int r = 0; r < 4; ++r) {
                const int ci = ci0 + wm * 64 + tm * 16 + (lane >> 4) * 4 + r;
                epart[(long)slot * MM + b * TT + ci] = part[tm][r];
            }
    }
}

// ---------------------------------------------------------------------------
// softmax over the compacted (unmasked) set; masked t's get score 0.
__global__ void softmax_kernel(const float* __restrict__ epart,
                               const int* __restrict__ rowlist,
                               const int* __restrict__ cnts,
                               float* __restrict__ score) {
    const int b = blockIdx.x, tid = threadIdx.x;   // 32 x 256
    const int cnt = cnts[b];
    for (int t = tid; t < TT; t += 256) score[b * TT + t] = 0.0f;

    float e[8], mx = -1e30f;
#pragma unroll
    for (int i = 0; i < 8; ++i) {
        const int ci = i * 256 + tid;
        float sum = -1e30f;
        if (ci < cnt) {
            sum = 0.f;
#pragma unroll
            for (int p = 0; p < 16; ++p)
                sum += epart[(long)p * MM + b * TT + ci];
        }
        e[i] = sum;
        mx = fmaxf(mx, sum);
    }
#pragma unroll
    for (int off = 32; off > 0; off >>= 1) mx = fmaxf(mx, __shfl_xor(mx, off, 64));
    __shared__ float r4[4];
    if ((tid & 63) == 0) r4[tid >> 6] = mx;
    __syncthreads();
    mx = fmaxf(fmaxf(r4[0], r4[1]), fmaxf(r4[2], r4[3]));

    float tot = 0.f;
#pragma unroll
    for (int i = 0; i < 8; ++i) {
        const int ci = i * 256 + tid;
        e[i] = (ci < cnt) ? __expf(e[i] - mx) : 0.0f;
        tot += e[i];
    }
#pragma unroll
    for (int off = 32; off > 0; off >>= 1) tot += __shfl_xor(tot, off, 64);
    __shared__ float s4[4];
    if ((tid & 63) == 0) s4[tid >> 6] = tot;
    __syncthreads();                                // also orders the zero-fill
    tot = s4[0] + s4[1] + s4[2] + s4[3];
    const float inv = 1.0f / tot;
#pragma unroll
    for (int i = 0; i < 8; ++i) {
        const int ci = i * 256 + tid;
        if (ci < cnt)
            score[b * TT + rowlist[b * TT + ci]] = e[i] * inv;
    }
}

// ---------------------------------------------------------------------------
// context[b][d] = sum_t score·h16 ; score==0 (masked) rows skipped
__global__ void context_kernel(const _Float16* __restrict__ h16,
                               const float* __restrict__ score,
                               float* __restrict__ out) {
    const int tc = blockIdx.x;                 // 16 chunks x 128 t
    const int b  = blockIdx.y;
    const int d0 = threadIdx.x * 8;            // 128 thr x 8
    float a[8];
#pragma unroll
    for (int j = 0; j < 8; ++j) a[j] = 0.f;
    for (int i = 0; i < 128; ++i) {
        const int t = tc * 128 + i;
        const float sc = score[(long)b * TT + t];
        if (sc != 0.0f) {
            const half8 hv = *(const half8*)(h16 + ((long)(b * TT + t)) * DD + d0);
#pragma unroll
            for (int j = 0; j < 8; ++j) a[j] += sc * (float)hv[j];
        }
    }
#pragma unroll
    for (int j = 0; j < 8; ++j) atomicAdd(&out[b * DD + d0 + j], a[j]);
}

// ---------------------------------------------------------------------------
extern "C" void kernel_launch(void* const* d_in, const int* in_sizes, int n_in,
                              void* d_out, int out_size, void* d_ws, size_t ws_size,
                              hipStream_t stream) {
    const float* s    = (const float*)d_in[0];
    const float* h    = (const float*)d_in[1];
    const int*   mask = (const int*)  d_in[2];
    const float* W    = (const float*)d_in[3];
    const float* U    = (const float*)d_in[4];
    const float* v    = (const float*)d_in[5];
    float* out = (float*)d_out;

    // workspace layout (~135 MB)
    char* ws = (char*)d_ws;
    size_t off = 0;
    _Float16* h16 = (_Float16*)(ws + off); off += (size_t)MM * DD * 2;   // 128 MB
    _Float16* Ut  = (_Float16*)(ws + off); off += (size_t)HH * DD * 2;   // 2 MB
    float*    ps  = (float*)(ws + off);    off += (size_t)BB * HH * 4;   // 128 KB
    float*    ep  = (float*)(ws + off);    off += (size_t)16 * MM * 4;   // 4 MB
    float*    scr = (float*)(ws + off);    off += (size_t)MM * 4;        // 256 KB
    int*      rlist = (int*)(ws + off);    off += (size_t)MM * 4;        // 256 KB
    int*      cnts  = (int*)(ws + off);    off += 64 * 4;

    mega_setup_kernel<<<TOTAL_SETUP, 256, 0, stream>>>(h, mask, h16, U, Ut,
                                                       s, W, ps, out, rlist, cnts);
    energy_gemm_kernel<<<dim3(8, 512), 256, 0, stream>>>(h16, Ut, ps, v,
                                                         rlist, cnts, ep);
    softmax_kernel<<<BB, 256, 0, stream>>>(ep, rlist, cnts, scr);
    context_kernel<<<dim3(16, 32), 128, 0, stream>>>(h16, scr, out);
}